// Round 14
// baseline (95.964 us; speedup 1.0000x reference)
//
#include <hip/hip_runtime.h>
#include <hip/hip_bf16.h>

typedef float f32x4 __attribute__((ext_vector_type(4)));
typedef unsigned int u32x4 __attribute__((ext_vector_type(4)));
typedef short s16x8 __attribute__((ext_vector_type(8)));

#define L2E 1.44269504088896340736f

static __device__ __forceinline__ unsigned int bf16_rne(float f) {
    unsigned int u = __builtin_bit_cast(unsigned int, f);
    return (u + 0x7fffu + ((u >> 16) & 1u)) >> 16;
}
static __device__ __forceinline__ unsigned int pack_bf16x2(float lo, float hi) {
    return bf16_rne(lo) | (bf16_rne(hi) << 16);
}
static __device__ __forceinline__ unsigned int cvt_pk_bf16(float lo, float hi) {
    unsigned int r;
    asm("v_cvt_pk_bf16_f32 %0, %1, %2" : "=v"(r) : "v"(lo), "v"(hi));
    return r;
}

// ---------------------------------------------------------------------------
// Prep (verbatim from the Round-8 passing kernel):
// q' = (q+pos)*0.125*log2e -> bf16 [b][t][c]; k',v' -> fragment-major bf16.
// ---------------------------------------------------------------------------
__global__ __launch_bounds__(256) void qkv_prep(const float* __restrict__ qkv,
                                                const float* __restrict__ pos,
                                                unsigned short* __restrict__ qs,
                                                unsigned short* __restrict__ ktf,
                                                unsigned short* __restrict__ vtf)
{
    __shared__ unsigned short QtS[64][72];
    __shared__ unsigned short KtS[64][72];
    const int b    = blockIdx.y;
    const int t0   = blockIdx.x * 64;
    const int i    = threadIdx.x;
    const int crow = i >> 2;
    const int t16  = (i & 3) * 16;
    const float QSCALE = 0.125f * L2E;

    float pr[16];
    {
        const f32x4* pp = reinterpret_cast<const f32x4*>(
            pos + ((size_t)(b * 64 + crow)) * 2048 + t0 + t16);
        #pragma unroll
        for (int j = 0; j < 4; ++j) {
            f32x4 v = __builtin_nontemporal_load(pp + j);
            pr[4*j+0] = v[0]; pr[4*j+1] = v[1]; pr[4*j+2] = v[2]; pr[4*j+3] = v[3];
        }
    }
    const float* qp = qkv + ((size_t)(b * 192 + crow)) * 2048 + t0 + t16;
    {
        #pragma unroll
        for (int j = 0; j < 4; ++j) {
            f32x4 v = __builtin_nontemporal_load(reinterpret_cast<const f32x4*>(qp) + j);
            #pragma unroll
            for (int e = 0; e < 4; ++e)
                QtS[t16 + 4*j + e][crow] =
                    (unsigned short)bf16_rne((v[e] + pr[4*j+e]) * QSCALE);
        }
    }
    {
        const float* kp = qp + (size_t)64 * 2048;
        #pragma unroll
        for (int j = 0; j < 4; ++j) {
            f32x4 v = __builtin_nontemporal_load(reinterpret_cast<const f32x4*>(kp) + j);
            #pragma unroll
            for (int e = 0; e < 4; ++e)
                KtS[t16 + 4*j + e][crow] =
                    (unsigned short)bf16_rne(v[e] + pr[4*j+e]);
        }
    }
    {   // V: pack and write fragment-major directly
        const float* vp = qp + (size_t)128 * 2048;
        unsigned int vv[8];
        #pragma unroll
        for (int j = 0; j < 4; ++j) {
            f32x4 v = __builtin_nontemporal_load(reinterpret_cast<const f32x4*>(vp) + j);
            vv[2*j+0] = pack_bf16x2(v[0] + pr[4*j+0], v[1] + pr[4*j+1]);
            vv[2*j+1] = pack_bf16x2(v[2] + pr[4*j+2], v[3] + pr[4*j+3]);
        }
        const int n   = crow >> 4;
        const int lnv = crow & 15;
        const int sb  = t0 >> 6;
        #pragma unroll
        for (int h = 0; h < 2; ++h) {
            const int soff = t16 + 8 * h;
            const int kc2  = soff >> 5;
            const int lgv  = (soff >> 3) & 3;
            unsigned short* dst = vtf +
                ((((size_t)(b * 32 + sb)) * 4 + n) * 2 + kc2) * 512 +
                (lnv + 16 * lgv) * 8;
            *reinterpret_cast<u32x4*>(dst) =
                (u32x4){vv[4*h+0], vv[4*h+1], vv[4*h+2], vv[4*h+3]};
        }
    }
    __syncthreads();
    {   // Q out [t][c] linear
        const int trow = i >> 2;
        const int c16  = (i & 3) * 16;
        u32x4 a0 = *reinterpret_cast<const u32x4*>(&QtS[trow][c16]);
        u32x4 a1 = *reinterpret_cast<const u32x4*>(&QtS[trow][c16 + 8]);
        unsigned short* qd = qs + ((size_t)(b * 2048 + t0 + trow)) * 64 + c16;
        reinterpret_cast<u32x4*>(qd)[0] = a0;
        reinterpret_cast<u32x4*>(qd)[1] = a1;
    }
    {   // K out fragment-major
        const int g   = i >> 6;
        const int l   = i & 63;
        const int lnk = l & 15;
        const int lgk = l >> 4;
        #pragma unroll
        for (int kc = 0; kc < 2; ++kc) {
            u32x4 d = *reinterpret_cast<const u32x4*>(
                &KtS[16 * g + lnk][32 * kc + 8 * lgk]);
            unsigned short* dst = ktf +
                (((size_t)(b * 128 + (t0 >> 4) + g)) * 2 + kc) * 512 + l * 8;
            *reinterpret_cast<u32x4*>(dst) = d;
        }
    }
}

// ---------------------------------------------------------------------------
// Mask -> bitmask [b][t][s/16] (ushort), fully coalesced (verbatim from R8).
// ---------------------------------------------------------------------------
__global__ __launch_bounds__(256) void mask_pack(const void* __restrict__ maskp,
                                                 unsigned short* __restrict__ mbits)
{
    const int b   = blockIdx.y;
    const int row = blockIdx.x * 2 + (threadIdx.x >> 7);
    const int c16 = threadIdx.x & 127;

    unsigned int accm = 0;
    {
        const unsigned int* mu = (const unsigned int*)maskp;
        #pragma unroll
        for (int j = 0; j < 16; ++j) accm |= mu[j];
    }
    unsigned int v = 0;
    const size_t rowbase = (size_t)b * 2048 + (size_t)row;
    if ((accm & 0xffffff00u) != 0u) {       // bool bytes
        u32x4 x = *reinterpret_cast<const u32x4*>(
            (const unsigned char*)maskp + rowbase * 2048 + c16 * 16);
        #pragma unroll
        for (int w = 0; w < 4; ++w)
            #pragma unroll
            for (int e = 0; e < 4; ++e)
                v |= (((x[w] >> (8 * e)) & 0xffu) ? 1u : 0u) << (4 * w + e);
    } else {                                 // int32 0/1
        const u32x4* src = reinterpret_cast<const u32x4*>(
            (const unsigned int*)maskp + rowbase * 2048 + c16 * 16);
        #pragma unroll
        for (int w = 0; w < 4; ++w) {
            u32x4 x = src[w];
            #pragma unroll
            for (int e = 0; e < 4; ++e)
                v |= (x[e] ? 1u : 0u) << (4 * w + e);
        }
    }
    mbits[rowbase * 128 + c16] = (unsigned short)v;
}

// ---------------------------------------------------------------------------
// Flash attention: BYTE-IDENTICAL to the Round-8 passing kernel except the
// block-index mapping (XCD-aware bijective swizzle replaces 2D grid).
// Fragment-major LDS (conflict-free), exp2-only softmax, permlane P
// redistribute, double-buffered, 1 barrier/iter, per-lane register mask.
// ---------------------------------------------------------------------------
__global__ __launch_bounds__(256) void attn_kernel(const unsigned short* __restrict__ qs,
                                                   const unsigned short* __restrict__ ktf,
                                                   const unsigned short* __restrict__ vtf,
                                                   const unsigned short* __restrict__ mbits,
                                                   float* __restrict__ out)
{
    __shared__ unsigned short KldsF[2][4096];   // 8KB per buf, fragment-major
    __shared__ unsigned short VldsF[2][4096];

    // XCD swizzle (bijective over id 0..511): XCD (id&7) hosts batches
    // {2*(id&7), 2*(id&7)+1} only -> per-XCD L2 working set ~2.6MB < 4MB.
    const int id   = blockIdx.x;
    const int xcd  = id & 7;
    const int sq   = id >> 3;             // 0..63
    const int b    = xcd * 2 + (sq >> 5); // 0..15, each (b,t0) hit once
    const int t0   = (sq & 31) * 64;

    const int tid  = threadIdx.x;
    const int wave = tid >> 6;
    const int lane = tid & 63;
    const int ln   = lane & 15;
    const int lg   = lane >> 4;
    const int tg   = t0 + 16 * wave + ln;      // this lane's q row

    s16x8 qf[2];
    #pragma unroll
    for (int kc = 0; kc < 2; ++kc)
        qf[kc] = *reinterpret_cast<const s16x8*>(
            qs + ((size_t)(b * 2048 + tg)) * 64 + 32 * kc + 8 * lg);

    f32x4 acc[4];
    #pragma unroll
    for (int n = 0; n < 4; ++n) acc[n] = (f32x4){0.f, 0.f, 0.f, 0.f};
    float L = 0.0f;

    const unsigned short* kbase = ktf + ((size_t)b * 256) * 512;
    const unsigned short* vbase = vtf + ((size_t)b * 32) * 4096;
    const unsigned short* mrowp = mbits + ((size_t)b * 2048 + (size_t)tg) * 128;

    unsigned long long mq_cur;

    {   // prologue: stage tile 0 + its mask bits
        u32x4 k0 = *reinterpret_cast<const u32x4*>(kbase + tid * 8);
        u32x4 k1 = *reinterpret_cast<const u32x4*>(kbase + 2048 + tid * 8);
        u32x4 v0 = *reinterpret_cast<const u32x4*>(vbase + tid * 8);
        u32x4 v1 = *reinterpret_cast<const u32x4*>(vbase + 2048 + tid * 8);
        mq_cur = *reinterpret_cast<const unsigned long long*>(mrowp);
        *reinterpret_cast<u32x4*>(&KldsF[0][tid * 8])        = k0;
        *reinterpret_cast<u32x4*>(&KldsF[0][2048 + tid * 8]) = k1;
        *reinterpret_cast<u32x4*>(&VldsF[0][tid * 8])        = v0;
        *reinterpret_cast<u32x4*>(&VldsF[0][2048 + tid * 8]) = v1;
    }
    __syncthreads();

    int cur = 0;
    for (int st = 0; st < 32; ++st) {
        // prefetch tile st+1 into registers
        u32x4 k0, k1, v0, v1;
        unsigned long long mq_nxt;
        const bool pf = (st < 31);
        if (pf) {
            const unsigned short* ks = kbase + (size_t)(st + 1) * 4096;
            const unsigned short* vs = vbase + (size_t)(st + 1) * 4096;
            k0 = *reinterpret_cast<const u32x4*>(ks + tid * 8);
            k1 = *reinterpret_cast<const u32x4*>(ks + 2048 + tid * 8);
            v0 = *reinterpret_cast<const u32x4*>(vs + tid * 8);
            v1 = *reinterpret_cast<const u32x4*>(vs + 2048 + tid * 8);
            mq_nxt = *reinterpret_cast<const unsigned long long*>(mrowp + (st + 1) * 4);
        }

        // QK^T (swapped): conflict-free fragment reads
        f32x4 S[4];
        #pragma unroll
        for (int ti = 0; ti < 4; ++ti) S[ti] = (f32x4){0.f, 0.f, 0.f, 0.f};
        __builtin_amdgcn_s_setprio(1);
        #pragma unroll
        for (int kc = 0; kc < 2; ++kc) {
            #pragma unroll
            for (int ti = 0; ti < 4; ++ti) {
                s16x8 kf = *reinterpret_cast<const s16x8*>(
                    &KldsF[cur][(ti * 2 + kc) * 512 + lane * 8]);
                S[ti] = __builtin_amdgcn_mfma_f32_16x16x32_bf16(kf, qf[kc], S[ti], 0, 0, 0);
            }
        }
        __builtin_amdgcn_s_setprio(0);

        // mask + unnormalized exp2 (lane-local; no cross-lane dependency)
        const unsigned long long shq = mq_cur >> (4 * lg);
        const unsigned int wlo = (unsigned int)shq;          // bits for ti=0,1
        const unsigned int whi = (unsigned int)(shq >> 32);  // bits for ti=2,3
        float p[4][4];
        #pragma unroll
        for (int ti = 0; ti < 4; ++ti) {
            const unsigned int w = (ti < 2) ? wlo : whi;
            const int base = 16 * (ti & 1);
            #pragma unroll
            for (int r = 0; r < 4; ++r) {
                const float s = ((w >> (base + r)) & 1u) ? -16384.0f : S[ti][r];
                p[ti][r] = __builtin_amdgcn_exp2f(s);
                L += p[ti][r];
            }
        }

        // pack P -> bf16; redistribute via permlane (VALU pipe)
        unsigned int pk[4][2];
        #pragma unroll
        for (int ti = 0; ti < 4; ++ti) {
            pk[ti][0] = cvt_pk_bf16(p[ti][0], p[ti][1]);
            pk[ti][1] = cvt_pk_bf16(p[ti][2], p[ti][3]);
        }
        unsigned int pfr[2][4];
        #pragma unroll
        for (int kc2 = 0; kc2 < 2; ++kc2) {
            #pragma unroll
            for (int b2 = 0; b2 < 2; ++b2) {
                unsigned int x = pk[2 * kc2 + 0][b2];
                unsigned int y = pk[2 * kc2 + 1][b2];
                asm("v_permlane32_swap_b32 %0, %1" : "+v"(x), "+v"(y));
                asm("v_permlane16_swap_b32 %0, %1" : "+v"(x), "+v"(y));
                pfr[kc2][0 + b2] = x;
                pfr[kc2][2 + b2] = y;
            }
        }

        // PV: conflict-free fragment reads
        __builtin_amdgcn_s_setprio(1);
        #pragma unroll
        for (int kc2 = 0; kc2 < 2; ++kc2) {
            union { unsigned int u[4]; s16x8 s; } pu;
            pu.u[0] = pfr[kc2][0]; pu.u[1] = pfr[kc2][1];
            pu.u[2] = pfr[kc2][2]; pu.u[3] = pfr[kc2][3];
            #pragma unroll
            for (int n = 0; n < 4; ++n) {
                s16x8 vf = *reinterpret_cast<const s16x8*>(
                    &VldsF[cur][(n * 2 + kc2) * 512 + lane * 8]);
                acc[n] = __builtin_amdgcn_mfma_f32_16x16x32_bf16(vf, pu.s, acc[n], 0, 0, 0);
            }
        }
        __builtin_amdgcn_s_setprio(0);

        // write prefetched tile; single barrier
        if (pf) {
            *reinterpret_cast<u32x4*>(&KldsF[cur ^ 1][tid * 8])        = k0;
            *reinterpret_cast<u32x4*>(&KldsF[cur ^ 1][2048 + tid * 8]) = k1;
            *reinterpret_cast<u32x4*>(&VldsF[cur ^ 1][tid * 8])        = v0;
            *reinterpret_cast<u32x4*>(&VldsF[cur ^ 1][2048 + tid * 8]) = v1;
            mq_cur = mq_nxt;
            __syncthreads();
            cur ^= 1;
        }
    }

    // epilogue: single cross-lane L reduce, normalize, coalesced store
    float Lr = L;
    Lr += __shfl_xor(Lr, 16, 64);
    Lr += __shfl_xor(Lr, 32, 64);
    const float inv = 1.0f / Lr;
    #pragma unroll
    for (int n = 0; n < 4; ++n)
        #pragma unroll
        for (int r = 0; r < 4; ++r)
            __builtin_nontemporal_store(
                acc[n][r] * inv,
                &out[((size_t)(b * 64 + 16 * n + 4 * lg + r)) * 2048 + tg]);
}

extern "C" void kernel_launch(void* const* d_in, const int* in_sizes, int n_in,
                              void* d_out, int out_size, void* d_ws, size_t ws_size,
                              hipStream_t stream) {
    const float* qkv = (const float*)d_in[0];
    const float* pos = (const float*)d_in[1];
    const void*  msk = d_in[2];
    float* outp = (float*)d_out;
    unsigned short* ws = (unsigned short*)d_ws;
    const size_t PLANE = (size_t)16 * 2048 * 64;   // 2M shorts per plane
    unsigned short* qs    = ws;
    unsigned short* ktf   = ws + PLANE;
    unsigned short* vtf   = ws + 2 * PLANE;
    unsigned short* mbits = ws + 3 * PLANE;        // 16*2048*128 ushorts = 8.4MB

    dim3 grid(2048 / 64, 16);
    qkv_prep <<<grid, 256, 0, stream>>>(qkv, pos, qs, ktf, vtf);
    mask_pack<<<dim3(1024, 16), 256, 0, stream>>>(msk, mbits);
    attn_kernel<<<512, 256, 0, stream>>>(qs, ktf, vtf, mbits, outp);
}